// Round 9
// baseline (1051836.621 us; speedup 1.0000x reference)
//
#include <hip/hip_runtime.h>
#include <stdint.h>

#define NN 4096
#define DD 64
#define GCOL 16
#define CCH 16
#define RCHK 8
#define TMAX 112
#define NROUNDS 20
#define ROUNDS_FB 32

typedef unsigned long long u64;
typedef unsigned int u32;

#define RESC 0xFFFFFFFFFFFFFFFEull
#define EMPTY (~0ull)

__device__ __forceinline__ u64 pk(float d, u32 idx) {
  return (((u64)__float_as_uint(d)) << 32) | (u64)idx;
}

__device__ __forceinline__ float distfly(const float* __restrict__ x,
                                         const float* __restrict__ y,
                                         float xxi, float yyj, int i, int j) {
  const float* xi = x + (size_t)i * DD;
  const float* yj = y + (size_t)j * DD;
  float dot = 0.f;
#pragma unroll
  for (int k = 0; k < DD; ++k) dot = fmaf(xi[k], yj[k], dot);
  float sq = (xxi + yyj) - 2.0f * dot;
  return sqrtf(fmaxf(sq, 0.f));
}

__global__ void k_init(const float* __restrict__ x, const float* __restrict__ y,
                       float* xx, float* yy, int* rm, int* cm, int* FR, int* Fcnt,
                       u64* rowbest, u64* rowpart, u64* colpart) {
  int i = blockIdx.x * blockDim.x + threadIdx.x;
  if (i < NN) {
    const float* xi = x + (size_t)i * DD;
    const float* yi = y + (size_t)i * DD;
    float sx = 0.f, sy = 0.f;
#pragma unroll
    for (int k = 0; k < DD; ++k) { sx = fmaf(xi[k], xi[k], sx); sy = fmaf(yi[k], yi[k], sy); }
    xx[i] = sx; yy[i] = sy;
    rm[i] = -1; cm[i] = -1; FR[i] = i;
    rowbest[i] = EMPTY;
#pragma unroll
    for (int h = 0; h < RCHK; ++h) rowpart[(size_t)h * NN + i] = RESC;
#pragma unroll
    for (int g = 0; g < CCH; ++g) colpart[(size_t)g * NN + i] = RESC;
    if (i == 0) *Fcnt = NN;
  }
}

// C build, LDS-transposed for ds_read_b128 operand fetch; fmaf chain order
// identical to all prior (proven bit-exact) rounds. SEED: private per-tile
// row/col minima (no atomics).
template <bool SEED>
__global__ void k_build(const float* __restrict__ x, const float* __restrict__ y,
                        const float* __restrict__ xx, const float* __restrict__ yy,
                        float* __restrict__ C, u64* __restrict__ tilerow,
                        u64* __restrict__ tilecol) {
  __shared__ __align__(16) float xs_t[64][68];   // [k][row], pad 68 -> 16B-aligned float4
  __shared__ __align__(16) float ys_t[64][68];   // [k][col]
  __shared__ u64 colred[16][65];
  int t = threadIdx.x;
  int bi = blockIdx.y * 64, bj = blockIdx.x * 64;
  for (int e = t; e < 64 * 64; e += 256) {
    int r = e >> 6, c = e & 63;                  // global read coalesced; LDS write transposed
    xs_t[c][r] = x[(size_t)(bi + r) * DD + c];
    ys_t[c][r] = y[(size_t)(bj + r) * DD + c];
  }
  __syncthreads();
  int tx = t & 15, ty = t >> 4;
  float acc[4][4];
#pragma unroll
  for (int r = 0; r < 4; ++r)
#pragma unroll
    for (int c = 0; c < 4; ++c) acc[r][c] = 0.f;
#pragma unroll
  for (int k = 0; k < 64; ++k) {
    float4 av = *(const float4*)&xs_t[k][ty * 4];
    float4 bv = *(const float4*)&ys_t[k][tx * 4];
    const float* a = (const float*)&av;
    const float* b = (const float*)&bv;
#pragma unroll
    for (int r = 0; r < 4; ++r)
#pragma unroll
      for (int c = 0; c < 4; ++c) acc[r][c] = fmaf(a[r], b[c], acc[r][c]);
  }
  u64 ck[4] = {EMPTY, EMPTY, EMPTY, EMPTY};
#pragma unroll
  for (int r = 0; r < 4; ++r) {
    int i = bi + ty * 4 + r;
    float xxi = xx[i];
    float4 v;
    float* vp = (float*)&v;
    u64 rkey = EMPTY;
#pragma unroll
    for (int c = 0; c < 4; ++c) {
      int j = bj + tx * 4 + c;
      float sq = (xxi + yy[j]) - 2.0f * acc[r][c];
      float d = sqrtf(fmaxf(sq, 0.f));
      vp[c] = d;
      if (SEED) {
        u64 kr = pk(d, (u32)j);
        if (kr < rkey) rkey = kr;
        u64 kc = pk(d, (u32)i);
        if (kc < ck[c]) ck[c] = kc;
      }
    }
    *(float4*)(C + (size_t)i * NN + bj + tx * 4) = v;
    if (SEED) {
#pragma unroll
      for (int md = 1; md < 16; md <<= 1) {
        u64 o = __shfl_xor(rkey, md, 64);
        if (o < rkey) rkey = o;
      }
      if (tx == 0) tilerow[(size_t)blockIdx.x * NN + i] = rkey;
    }
  }
  if (SEED) {
#pragma unroll
    for (int c = 0; c < 4; ++c) colred[ty][tx * 4 + c] = ck[c];
    __syncthreads();
    if (t < 64) {
      u64 m = colred[0][t];
#pragma unroll
      for (int k = 1; k < 16; ++k) if (colred[k][t] < m) m = colred[k][t];
      tilecol[(size_t)blockIdx.y * NN + bj + t] = m;
    }
  }
}

// Reduce private tile minima into rowbest/rowpart/colpart (all rows/cols free).
__global__ void k_seed(const u64* __restrict__ tilerow, const u64* __restrict__ tilecol,
                       u64* rowbest, u64* rowpart, u64* colpart) {
  int v = blockIdx.x * 256 + threadIdx.x;
  if (v < NN) {
    int i = v;
    u64 best = EMPTY;
#pragma unroll
    for (int h = 0; h < RCHK; ++h) {
      u64 m = EMPTY;
      for (int bx = h * 8; bx < h * 8 + 8; ++bx) {
        u64 e = tilerow[(size_t)bx * NN + i];
        if (e < m) m = e;
      }
      rowpart[(size_t)h * NN + i] = m;
      if (m < best) best = m;
    }
    rowbest[i] = best;
  } else if (v < 2 * NN) {
    int j = v - NN;
#pragma unroll
    for (int g = 0; g < CCH; ++g) {
      u64 m = EMPTY;
      for (int by = g * 4; by < g * 4 + 4; ++by) {
        u64 e = tilecol[(size_t)by * NN + j];
        if (e < m) m = e;
      }
      colpart[(size_t)g * NN + j] = m;
    }
  }
}

// Fused round: blocks [0,16) accept (using existing caches; monotone invariant
// makes any interleaving safe -- accepts are always true mutual minima);
// blocks [16, 16+NN) row minima; blocks [16+NN, 16+NN+1024) col-chunk minima.
__global__ void k_fused(const float* __restrict__ C, int* rm, int* cm,
                        u64* __restrict__ rowbest, u64* __restrict__ rowpart,
                        u64* __restrict__ colpart, int* Fcnt) {
  __shared__ u64 red[256];
  __shared__ u64 rp[RCHK];
  __shared__ int stale[RCHK];
  __shared__ u64 part[4][64];
  int b = blockIdx.x;
  int t = threadIdx.x;
  if (b < 16) {
    // ---- accept role ----
    if (*Fcnt == 0) return;
    int j = b * 256 + t;
    if (cm[j] != -1) return;
    u64 best = EMPTY;
#pragma unroll
    for (int g = 0; g < CCH; ++g) {
      u64 v = colpart[(size_t)g * NN + j];
      if (v < best) best = v;
    }
    u32 io = (u32)best;
    if (io >= NN) return;
    int i = (int)io;
    if (rm[i] == -1 && (u32)(rowbest[i] & 0xffffffffu) == (u32)j) {
      rm[i] = j; cm[j] = i;
      atomicSub(Fcnt, 1);
    }
  } else if (b < 16 + NN) {
    // ---- row minima role (proven k_round2 logic) ----
    int i = b - 16;
    if (rm[i] != -1) return;
    u64 rb = rowbest[i];
    u32 jb = (u32)rb;
    if (jb < NN && cm[jb] == -1) return;
    if (t < RCHK) {
      u64 e = rowpart[(size_t)t * NN + i];
      rp[t] = e;
      u32 je = (u32)e;
      stale[t] = (e != EMPTY) && !(je < NN && cm[je] == -1);
    }
    __syncthreads();
    const float* Ci = C + (size_t)i * NN;
    for (int h = 0; h < RCHK; ++h) {
      if (!stale[h]) continue;
      int j0 = h * 512 + t * 2;
      float2 v = *(const float2*)(Ci + j0);
      int2 m = *(const int2*)(cm + j0);
      u64 best = EMPTY;
      if (m.x == -1) best = pk(v.x, (u32)j0);
      if (m.y == -1) { u64 k2 = pk(v.y, (u32)(j0 + 1)); if (k2 < best) best = k2; }
      red[t] = best;
      __syncthreads();
      for (int s = 128; s > 0; s >>= 1) {
        if (t < s) { if (red[t + s] < red[t]) red[t] = red[t + s]; }
        __syncthreads();
      }
      if (t == 0) { rp[h] = red[0]; rowpart[(size_t)h * NN + i] = red[0]; }
      __syncthreads();
    }
    if (t == 0) {
      u64 best = rp[0];
#pragma unroll
      for (int h = 1; h < RCHK; ++h) if (rp[h] < best) best = rp[h];
      rowbest[i] = best;
    }
  } else {
    // ---- col-chunk minima role (proven k_round2 logic) ----
    int idx = b - 16 - NN;
    int cb = idx & 63, g = idx >> 6;
    int lane = t & 63, s = t >> 6;
    int j = cb * 64 + lane;
    u64* slot = colpart + (size_t)g * NN + j;
    bool stale_c = false;
    if (cm[j] == -1) {
      u64 e = *slot;
      if (e != EMPTY) { u32 io = (u32)e; stale_c = !(io < NN && rm[io] == -1); }
    }
    u64 best = EMPTY;
    if (stale_c) {
      int i0 = g * 256 + s * 64;
      for (int i = i0; i < i0 + 64; ++i) {
        if (rm[i] != -1) continue;
        u64 key = pk(C[(size_t)i * NN + j], (u32)i);
        if (key < best) best = key;
      }
    }
    part[s][lane] = best;
    __syncthreads();
    if (s == 0 && stale_c) {
      u64 b0 = part[0][lane];
#pragma unroll
      for (int q = 1; q < 4; ++q) if (part[q][lane] < b0) b0 = part[q][lane];
      *slot = b0;
    }
  }
}

// Endgame (proven round 5): LDS submatrix greedy for F<=TMAX, else bounded global.
__global__ __launch_bounds__(256) void k_endgame(const float* __restrict__ C,
                                                 int* rm, int* cm, int* FRg) {
  __shared__ float Csub[TMAX * TMAX];
  __shared__ int sF, sG, sc_star, scnt;
  __shared__ int sFR[TMAX], sFC[TMAX];
  __shared__ u64 rkey[TMAX];
  __shared__ int rcol[TMAX];
  __shared__ int cfree[TMAX];
  __shared__ u64 wred[4];
  __shared__ u64 red[256];
  int t = threadIdx.x;
  if (t == 0) { sF = 0; sG = 0; }
  __syncthreads();
  for (int i = t; i < NN; i += 256)
    if (rm[i] == -1) { int p = atomicAdd(&sF, 1); if (p < TMAX) sFR[p] = i; }
  for (int j = t; j < NN; j += 256)
    if (cm[j] == -1) { int p = atomicAdd(&sG, 1); if (p < TMAX) sFC[p] = j; }
  __syncthreads();
  int F = sF;
  if (F == 0) return;
  if (F <= TMAX) {
    for (int r = (t >> 6); r < F; r += 4) {
      const float* Ci = C + (size_t)sFR[r] * NN;
      for (int c = (t & 63); c < F; c += 64) Csub[r * F + c] = Ci[sFC[c]];
    }
    for (int c = t; c < F; c += 256) cfree[c] = 1;
    __syncthreads();
    for (int r = t; r < F; r += 256) {
      const float* row = Csub + r * F;
      u64 bk = ~0ull; int bc = 0; int ig = sFR[r];
      for (int c = 0; c < F; ++c) {
        u64 k = (((u64)__float_as_uint(row[c])) << 24) | (u32)(ig * NN + sFC[c]);
        if (k < bk) { bk = k; bc = c; }
      }
      rkey[r] = bk; rcol[r] = bc;
    }
    __syncthreads();
    for (int it = 0; it < F; ++it) {
      u64 kb = ~0ull;
      if (t < F && rkey[t] != ~0ull) kb = (rkey[t] << 8) | (u64)(u32)t;
      for (int s = 32; s > 0; s >>= 1) {
        u64 o = __shfl_down(kb, s, 64);
        if (o < kb) kb = o;
      }
      if ((t & 63) == 0) wred[t >> 6] = kb;
      __syncthreads();
      if (t == 0) {
        u64 bmin = wred[0];
#pragma unroll
        for (int wv = 1; wv < 4; ++wv) if (wred[wv] < bmin) bmin = wred[wv];
        int rstar = (int)(bmin & 255);
        if (rstar >= F) rstar = 0;
        int cstar = rcol[rstar];
        sc_star = cstar;
        int i = sFR[rstar], j = sFC[cstar];
        rm[i] = j; cm[j] = i;
        rkey[rstar] = ~0ull; cfree[cstar] = 0;
      }
      __syncthreads();
      int cs = sc_star;
      for (int r = t; r < F; r += 256) {
        if (rkey[r] != ~0ull && rcol[r] == cs) {
          const float* row = Csub + r * F;
          u64 bk = ~0ull; int bc = 0; int ig = sFR[r];
          for (int c = 0; c < F; ++c) {
            if (!cfree[c]) continue;
            u64 k = (((u64)__float_as_uint(row[c])) << 24) | (u32)(ig * NN + sFC[c]);
            if (k < bk) { bk = k; bc = c; }
          }
          rkey[r] = bk; rcol[r] = bc;
        }
      }
      __syncthreads();
    }
  } else {
    for (int it = 0; it < NN; ++it) {
      if (t == 0) scnt = 0;
      __syncthreads();
      for (int i = t; i < NN; i += 256)
        if (rm[i] == -1) { int p = atomicAdd(&scnt, 1); FRg[p] = i; }
      __syncthreads();
      int Fa = scnt;
      if (Fa == 0) break;
      u64 best = ~0ull;
      int total = Fa * NN;
      for (int idx = t; idx < total; idx += 256) {
        int bb2 = idx >> 12, j = idx & 4095;
        if (cm[j] != -1) continue;
        int i = FRg[bb2];
        u64 key = pk(C[(size_t)i * NN + j], (u32)(i * NN + j));
        if (key < best) best = key;
      }
      red[t] = best;
      __syncthreads();
      for (int s = 128; s > 0; s >>= 1) {
        if (t < s) { if (red[t + s] < red[t]) red[t] = red[t + s]; }
        __syncthreads();
      }
      if (t == 0) {
        u32 lo = (u32)red[0];
        rm[lo >> 12] = lo & 4095; cm[lo & 4095] = lo >> 12;
      }
      __syncthreads();
    }
  }
}

// ---------- no-C fallback (proven round 1) ----------
template <bool USEC>
__global__ void k_rowpass(const float* __restrict__ C,
                          const float* __restrict__ x, const float* __restrict__ y,
                          const float* __restrict__ xx, const float* __restrict__ yy,
                          const int* __restrict__ cm, const int* __restrict__ FR,
                          const int* __restrict__ Fcnt, u64* __restrict__ rowbest) {
  int b = blockIdx.x;
  if (b >= *Fcnt) return;
  int i = FR[b];
  __shared__ float xsh[DD];
  __shared__ u64 red[256];
  int t = threadIdx.x;
  if (!USEC) { if (t < DD) xsh[t] = x[(size_t)i * DD + t]; }
  __syncthreads();
  float xxi = xx[i];
  u64 best = ~0ull;
  for (int j = t; j < NN; j += 256) {
    if (cm[j] != -1) continue;
    float d;
    if (USEC) {
      d = C[(size_t)i * NN + j];
    } else {
      const float* yj = y + (size_t)j * DD;
      float dot = 0.f;
#pragma unroll
      for (int k = 0; k < DD; ++k) dot = fmaf(xsh[k], yj[k], dot);
      float sq = (xxi + yy[j]) - 2.0f * dot;
      d = sqrtf(fmaxf(sq, 0.f));
    }
    u64 key = pk(d, (u32)j);
    if (key < best) best = key;
  }
  red[t] = best;
  __syncthreads();
  for (int s = 128; s > 0; s >>= 1) {
    if (t < s) { if (red[t + s] < red[t]) red[t] = red[t + s]; }
    __syncthreads();
  }
  if (t == 0) rowbest[i] = red[0];
}

template <bool USEC>
__global__ void k_colpass(const float* __restrict__ C,
                          const float* __restrict__ x, const float* __restrict__ y,
                          const float* __restrict__ xx, const float* __restrict__ yy,
                          const int* __restrict__ cm, const int* __restrict__ FR,
                          const int* __restrict__ Fcnt, u64* __restrict__ colpart) {
  int t = threadIdx.x;
  int j = blockIdx.x * 256 + t;
  int g = blockIdx.y;
  int F = *Fcnt;
  if (F == 0) return;
  int b0 = (g * F) / GCOL, b1 = ((g + 1) * F) / GCOL;
  u64 best = ~0ull;
  if (cm[j] == -1) {
    float yyj = yy[j];
    if (USEC) {
      for (int b = b0; b < b1; ++b) {
        int i = FR[b];
        u64 key = pk(C[(size_t)i * NN + j], (u32)i);
        if (key < best) best = key;
      }
    } else {
      float4 yr[16];
      const float4* yj4 = (const float4*)(y + (size_t)j * DD);
#pragma unroll
      for (int q = 0; q < 16; ++q) yr[q] = yj4[q];
      for (int b = b0; b < b1; ++b) {
        int i = FR[b];
        const float4* xi4 = (const float4*)(x + (size_t)i * DD);
        float dot = 0.f;
#pragma unroll
        for (int q = 0; q < 16; ++q) {
          float4 a = xi4[q], bb = yr[q];
          dot = fmaf(a.x, bb.x, dot); dot = fmaf(a.y, bb.y, dot);
          dot = fmaf(a.z, bb.z, dot); dot = fmaf(a.w, bb.w, dot);
        }
        float sq = (xx[i] + yyj) - 2.0f * dot;
        float d = sqrtf(fmaxf(sq, 0.f));
        u64 key = pk(d, (u32)i);
        if (key < best) best = key;
      }
    }
  }
  colpart[(size_t)g * NN + j] = best;
}

__global__ void k_accept(const u64* __restrict__ colpart, const u64* __restrict__ rowbest,
                         int* rm, int* cm, int* FR, int* Fcnt) {
  __shared__ int scnt;
  int t = threadIdx.x;
  if (*Fcnt == 0) return;
  for (int j = t; j < NN; j += 1024) {
    if (cm[j] != -1) continue;
    u64 best = ~0ull;
#pragma unroll
    for (int g = 0; g < GCOL; ++g) {
      u64 v = colpart[(size_t)g * NN + j];
      if (v < best) best = v;
    }
    u32 io = (u32)best;
    if (io >= NN) continue;
    int i = (int)io;
    if (rm[i] == -1 && (u32)(rowbest[i] & 0xffffffffu) == (u32)j) { rm[i] = j; cm[j] = i; }
  }
  __syncthreads();
  if (t == 0) scnt = 0;
  __syncthreads();
  for (int i = t; i < NN; i += 1024)
    if (rm[i] == -1) { int p = atomicAdd(&scnt, 1); FR[p] = i; }
  __syncthreads();
  if (t == 0) *Fcnt = scnt;
}

template <bool USEC>
__global__ void k_cleanup(const float* __restrict__ C,
                          const float* __restrict__ x, const float* __restrict__ y,
                          const float* __restrict__ xx, const float* __restrict__ yy,
                          int* rm, int* cm, int* FR) {
  __shared__ int scnt;
  __shared__ u64 red[1024];
  int t = threadIdx.x;
  for (int it = 0; it < NN; ++it) {
    if (t == 0) scnt = 0;
    __syncthreads();
    for (int i = t; i < NN; i += 1024)
      if (rm[i] == -1) { int p = atomicAdd(&scnt, 1); FR[p] = i; }
    __syncthreads();
    int F = scnt;
    if (F == 0) break;
    u64 best = ~0ull;
    int total = F * NN;
    for (int idx = t; idx < total; idx += 1024) {
      int b = idx >> 12;
      int j = idx & 4095;
      if (cm[j] != -1) continue;
      int i = FR[b];
      float d;
      if (USEC) d = C[(size_t)i * NN + j];
      else d = distfly(x, y, xx[i], yy[j], i, j);
      u64 key = pk(d, (u32)(i * NN + j));
      if (key < best) best = key;
    }
    red[t] = best;
    __syncthreads();
    for (int s = 512; s > 0; s >>= 1) {
      if (t < s) { if (red[t + s] < red[t]) red[t] = red[t + s]; }
      __syncthreads();
    }
    if (t == 0) {
      u32 lo = (u32)red[0];
      int i = lo >> 12, j = lo & 4095;
      rm[i] = j; cm[j] = i;
    }
    __syncthreads();
  }
}

extern "C" void kernel_launch(void* const* d_in, const int* in_sizes, int n_in,
                              void* d_out, int out_size, void* d_ws, size_t ws_size,
                              hipStream_t stream) {
  const float* x = (const float*)d_in[0];
  const float* y = (const float*)d_in[1];
  int* cm = (int*)d_out;

  char* w = (char*)d_ws;
  float* xx = (float*)(w + 0);
  float* yy = (float*)(w + 16384);
  int* rm = (int*)(w + 32768);
  int* FR = (int*)(w + 49152);
  int* Fcnt = (int*)(w + 65536);
  u64* rowbest = (u64*)(w + 65664);
  u64* rowpart = (u64*)(w + 98432);
  u64* colpart = (u64*)(w + 360704);
  float* C = (float*)(w + 1048576);
  u64* tilerow = (u64*)(w + 68157440);
  u64* tilecol = (u64*)(w + 70254592);

  size_t need_c = 1048576 + (size_t)NN * NN * 4;        // 68157440
  size_t need_seed = 68157440 + 2 * 2097152;            // 72351744
  bool usec = ws_size >= need_c;
  bool useseed = ws_size >= need_seed;

  k_init<<<dim3(16), 256, 0, stream>>>(x, y, xx, yy, rm, cm, FR, Fcnt,
                                       rowbest, rowpart, colpart);
  if (usec) {
    if (useseed) {
      k_build<true><<<dim3(64, 64), 256, 0, stream>>>(x, y, xx, yy, C, tilerow, tilecol);
      k_seed<<<dim3(32), 256, 0, stream>>>(tilerow, tilecol, rowbest, rowpart, colpart);
    } else {
      k_build<false><<<dim3(64, 64), 256, 0, stream>>>(x, y, xx, yy, C, nullptr, nullptr);
    }
    for (int r = 0; r < NROUNDS; ++r) {
      k_fused<<<dim3(16 + NN + 64 * CCH), 256, 0, stream>>>(C, rm, cm, rowbest,
                                                            rowpart, colpart, Fcnt);
    }
    k_endgame<<<dim3(1), 256, 0, stream>>>(C, rm, cm, FR);
  } else {
    for (int r = 0; r < ROUNDS_FB; ++r) {
      k_rowpass<false><<<dim3(NN), 256, 0, stream>>>(nullptr, x, y, xx, yy, cm, FR, Fcnt, rowbest);
      k_colpass<false><<<dim3(16, GCOL), 256, 0, stream>>>(nullptr, x, y, xx, yy, cm, FR, Fcnt, colpart);
      k_accept<<<dim3(1), 1024, 0, stream>>>(colpart, rowbest, rm, cm, FR, Fcnt);
    }
    k_cleanup<false><<<dim3(1), 1024, 0, stream>>>(nullptr, x, y, xx, yy, rm, cm, FR);
  }
}

// Round 10
// 2062.286 us; speedup vs baseline: 510.0344x; 510.0344x over previous
//
#include <hip/hip_runtime.h>
#include <stdint.h>

#define NN 4096
#define DD 64
#define GCOL 16
#define CCH 16
#define RCHK 8
#define TMAX 112
#define TGMAX 512
#define NROUNDS 19
#define ROUNDS_FB 32

typedef unsigned long long u64;
typedef unsigned int u32;

#define RESC 0xFFFFFFFFFFFFFFFEull
#define EMPTY (~0ull)

__device__ __forceinline__ u64 pk(float d, u32 idx) {
  return (((u64)__float_as_uint(d)) << 32) | (u64)idx;
}

__device__ __forceinline__ float distfly(const float* __restrict__ x,
                                         const float* __restrict__ y,
                                         float xxi, float yyj, int i, int j) {
  const float* xi = x + (size_t)i * DD;
  const float* yj = y + (size_t)j * DD;
  float dot = 0.f;
#pragma unroll
  for (int k = 0; k < DD; ++k) dot = fmaf(xi[k], yj[k], dot);
  float sq = (xxi + yyj) - 2.0f * dot;
  return sqrtf(fmaxf(sq, 0.f));
}

__global__ void k_init(const float* __restrict__ x, const float* __restrict__ y,
                       float* xx, float* yy, int* rm, int* cm, int* FR, int* Fcnt,
                       u64* rowbest, u64* rowpart, u64* colpart) {
  int i = blockIdx.x * blockDim.x + threadIdx.x;
  if (i < NN) {
    const float* xi = x + (size_t)i * DD;
    const float* yi = y + (size_t)i * DD;
    float sx = 0.f, sy = 0.f;
#pragma unroll
    for (int k = 0; k < DD; ++k) { sx = fmaf(xi[k], xi[k], sx); sy = fmaf(yi[k], yi[k], sy); }
    xx[i] = sx; yy[i] = sy;
    rm[i] = -1; cm[i] = -1; FR[i] = i;
    rowbest[i] = EMPTY;
#pragma unroll
    for (int h = 0; h < RCHK; ++h) rowpart[(size_t)h * NN + i] = RESC;
#pragma unroll
    for (int g = 0; g < CCH; ++g) colpart[(size_t)g * NN + i] = RESC;
    if (i == 0) *Fcnt = NN;
  }
}

// C build, LDS-transposed float4 operand fetch; fmaf chain order bit-identical.
// SEED: private per-tile row/col minima (no atomics).
template <bool SEED>
__global__ void k_build(const float* __restrict__ x, const float* __restrict__ y,
                        const float* __restrict__ xx, const float* __restrict__ yy,
                        float* __restrict__ C, u64* __restrict__ tilerow,
                        u64* __restrict__ tilecol) {
  __shared__ __align__(16) float xs_t[64][68];
  __shared__ __align__(16) float ys_t[64][68];
  __shared__ u64 colred[16][65];
  int t = threadIdx.x;
  int bi = blockIdx.y * 64, bj = blockIdx.x * 64;
  for (int e = t; e < 64 * 64; e += 256) {
    int r = e >> 6, c = e & 63;
    xs_t[c][r] = x[(size_t)(bi + r) * DD + c];
    ys_t[c][r] = y[(size_t)(bj + r) * DD + c];
  }
  __syncthreads();
  int tx = t & 15, ty = t >> 4;
  float acc[4][4];
#pragma unroll
  for (int r = 0; r < 4; ++r)
#pragma unroll
    for (int c = 0; c < 4; ++c) acc[r][c] = 0.f;
#pragma unroll
  for (int k = 0; k < 64; ++k) {
    float4 av = *(const float4*)&xs_t[k][ty * 4];
    float4 bv = *(const float4*)&ys_t[k][tx * 4];
    const float* a = (const float*)&av;
    const float* b = (const float*)&bv;
#pragma unroll
    for (int r = 0; r < 4; ++r)
#pragma unroll
      for (int c = 0; c < 4; ++c) acc[r][c] = fmaf(a[r], b[c], acc[r][c]);
  }
  u64 ck[4] = {EMPTY, EMPTY, EMPTY, EMPTY};
#pragma unroll
  for (int r = 0; r < 4; ++r) {
    int i = bi + ty * 4 + r;
    float xxi = xx[i];
    float4 v;
    float* vp = (float*)&v;
    u64 rkey = EMPTY;
#pragma unroll
    for (int c = 0; c < 4; ++c) {
      int j = bj + tx * 4 + c;
      float sq = (xxi + yy[j]) - 2.0f * acc[r][c];
      float d = sqrtf(fmaxf(sq, 0.f));
      vp[c] = d;
      if (SEED) {
        u64 kr = pk(d, (u32)j);
        if (kr < rkey) rkey = kr;
        u64 kc = pk(d, (u32)i);
        if (kc < ck[c]) ck[c] = kc;
      }
    }
    *(float4*)(C + (size_t)i * NN + bj + tx * 4) = v;
    if (SEED) {
#pragma unroll
      for (int md = 1; md < 16; md <<= 1) {
        u64 o = __shfl_xor(rkey, md, 64);
        if (o < rkey) rkey = o;
      }
      if (tx == 0) tilerow[(size_t)blockIdx.x * NN + i] = rkey;
    }
  }
  if (SEED) {
#pragma unroll
    for (int c = 0; c < 4; ++c) colred[ty][tx * 4 + c] = ck[c];
    __syncthreads();
    if (t < 64) {
      u64 m = colred[0][t];
#pragma unroll
      for (int k = 1; k < 16; ++k) if (colred[k][t] < m) m = colred[k][t];
      tilecol[(size_t)blockIdx.y * NN + bj + t] = m;
    }
  }
}

__global__ void k_seed(const u64* __restrict__ tilerow, const u64* __restrict__ tilecol,
                       u64* rowbest, u64* rowpart, u64* colpart) {
  int v = blockIdx.x * 256 + threadIdx.x;
  if (v < NN) {
    int i = v;
    u64 best = EMPTY;
#pragma unroll
    for (int h = 0; h < RCHK; ++h) {
      u64 m = EMPTY;
      for (int bx = h * 8; bx < h * 8 + 8; ++bx) {
        u64 e = tilerow[(size_t)bx * NN + i];
        if (e < m) m = e;
      }
      rowpart[(size_t)h * NN + i] = m;
      if (m < best) best = m;
    }
    rowbest[i] = best;
  } else if (v < 2 * NN) {
    int j = v - NN;
#pragma unroll
    for (int g = 0; g < CCH; ++g) {
      u64 m = EMPTY;
      for (int by = g * 4; by < g * 4 + 4; ++by) {
        u64 e = tilecol[(size_t)by * NN + j];
        if (e < m) m = e;
      }
      colpart[(size_t)g * NN + j] = m;
    }
  }
}

// Refresh (proven round-5 k_round2): blocks [0,NN) rows, [NN,NN+1024) col-chunks.
__global__ void k_round2(const float* __restrict__ C, const int* __restrict__ rm,
                         const int* __restrict__ cm, u64* __restrict__ rowbest,
                         u64* __restrict__ rowpart, u64* __restrict__ colpart) {
  __shared__ u64 red[256];
  __shared__ u64 rp[RCHK];
  __shared__ int stale[RCHK];
  __shared__ u64 part[4][64];
  int b = blockIdx.x;
  int t = threadIdx.x;
  if (b < NN) {
    int i = b;
    if (rm[i] != -1) return;
    u64 rb = rowbest[i];
    u32 jb = (u32)rb;
    if (jb < NN && cm[jb] == -1) return;
    if (t < RCHK) {
      u64 e = rowpart[(size_t)t * NN + i];
      rp[t] = e;
      u32 je = (u32)e;
      stale[t] = (e != EMPTY) && !(je < NN && cm[je] == -1);
    }
    __syncthreads();
    const float* Ci = C + (size_t)i * NN;
    for (int h = 0; h < RCHK; ++h) {
      if (!stale[h]) continue;
      int j0 = h * 512 + t * 2;
      float2 v = *(const float2*)(Ci + j0);
      int2 m = *(const int2*)(cm + j0);
      u64 best = EMPTY;
      if (m.x == -1) best = pk(v.x, (u32)j0);
      if (m.y == -1) { u64 k2 = pk(v.y, (u32)(j0 + 1)); if (k2 < best) best = k2; }
      red[t] = best;
      __syncthreads();
      for (int s = 128; s > 0; s >>= 1) {
        if (t < s) { if (red[t + s] < red[t]) red[t] = red[t + s]; }
        __syncthreads();
      }
      if (t == 0) { rp[h] = red[0]; rowpart[(size_t)h * NN + i] = red[0]; }
      __syncthreads();
    }
    if (t == 0) {
      u64 best = rp[0];
#pragma unroll
      for (int h = 1; h < RCHK; ++h) if (rp[h] < best) best = rp[h];
      rowbest[i] = best;
    }
  } else {
    int idx = b - NN;
    int cb = idx & 63, g = idx >> 6;
    int lane = t & 63, s = t >> 6;
    int j = cb * 64 + lane;
    u64* slot = colpart + (size_t)g * NN + j;
    bool stale_c = false;
    if (cm[j] == -1) {
      u64 e = *slot;
      if (e != EMPTY) { u32 io = (u32)e; stale_c = !(io < NN && rm[io] == -1); }
    }
    u64 best = EMPTY;
    if (stale_c) {
      int i0 = g * 256 + s * 64;
      for (int i = i0; i < i0 + 64; ++i) {
        if (rm[i] != -1) continue;
        u64 key = pk(C[(size_t)i * NN + j], (u32)i);
        if (key < best) best = key;
      }
    }
    part[s][lane] = best;
    __syncthreads();
    if (s == 0 && stale_c) {
      u64 b0 = part[0][lane];
#pragma unroll
      for (int q = 1; q < 4; ++q) if (part[q][lane] < b0) b0 = part[q][lane];
      *slot = b0;
    }
  }
}

__global__ void k_accept3(const u64* __restrict__ colpart, const u64* __restrict__ rowbest,
                          int* rm, int* cm, int* Fcnt) {
  if (*Fcnt == 0) return;
  int j = blockIdx.x * 256 + threadIdx.x;
  if (cm[j] != -1) return;
  u64 best = EMPTY;
#pragma unroll
  for (int g = 0; g < CCH; ++g) {
    u64 v = colpart[(size_t)g * NN + j];
    if (v < best) best = v;
  }
  u32 io = (u32)best;
  if (io >= NN) return;
  int i = (int)io;
  if (rm[i] == -1 && (u32)(rowbest[i] & 0xffffffffu) == (u32)j) {
    rm[i] = j; cm[j] = i;
    atomicSub(Fcnt, 1);
  }
}

// Endgame, 3 tiers: F<=TMAX LDS greedy; F<=TGMAX global-submatrix greedy with
// cached row minima (G = scratch, may be null); else bounded global fallback.
// Greedy order exact via key (cost<<24)|(i*NN+j); flat index fits 24 bits.
__global__ __launch_bounds__(256) void k_endgame(const float* __restrict__ C,
                                                 int* rm, int* cm, int* FRg,
                                                 float* __restrict__ G) {
  __shared__ __align__(16) char shb[54272];
  int* sFR5 = (int*)shb;                 // 512 ints
  int* sFC5 = (int*)(shb + 2048);        // 512 ints
  float* Csub = (float*)(shb + 4096);    // 112*112 floats (tier1)
  u64* rkey2 = (u64*)(shb + 4096);       // 512 u64 (tier2)
  int* rcol2 = (int*)(shb + 8192);       // 512 ints
  int* cfree2 = (int*)(shb + 10240);     // 512 ints
  int* dl = (int*)(shb + 12288);         // 512 ints
  __shared__ int sF, sG, sc_star, scnt;
  __shared__ u64 rkey[TMAX];
  __shared__ int rcol[TMAX];
  __shared__ int cfree[TMAX];
  __shared__ u64 wred[4];
  __shared__ u64 red[256];
  __shared__ int redi[256];
  int t = threadIdx.x;
  if (t == 0) { sF = 0; sG = 0; }
  __syncthreads();
  for (int i = t; i < NN; i += 256)
    if (rm[i] == -1) { int p = atomicAdd(&sF, 1); if (p < TGMAX) sFR5[p] = i; }
  for (int j = t; j < NN; j += 256)
    if (cm[j] == -1) { int p = atomicAdd(&sG, 1); if (p < TGMAX) sFC5[p] = j; }
  __syncthreads();
  int F = sF;
  if (F == 0) return;
  if (F <= TMAX) {
    for (int r = (t >> 6); r < F; r += 4) {
      const float* Ci = C + (size_t)sFR5[r] * NN;
      for (int c = (t & 63); c < F; c += 64) Csub[r * F + c] = Ci[sFC5[c]];
    }
    for (int c = t; c < F; c += 256) cfree[c] = 1;
    __syncthreads();
    for (int r = t; r < F; r += 256) {
      const float* row = Csub + r * F;
      u64 bk = ~0ull; int bc = 0; int ig = sFR5[r];
      for (int c = 0; c < F; ++c) {
        u64 k = (((u64)__float_as_uint(row[c])) << 24) | (u32)(ig * NN + sFC5[c]);
        if (k < bk) { bk = k; bc = c; }
      }
      rkey[r] = bk; rcol[r] = bc;
    }
    __syncthreads();
    for (int it = 0; it < F; ++it) {
      u64 kb = ~0ull;
      if (t < F && rkey[t] != ~0ull) kb = (rkey[t] << 8) | (u64)(u32)t;
      for (int s = 32; s > 0; s >>= 1) {
        u64 o = __shfl_down(kb, s, 64);
        if (o < kb) kb = o;
      }
      if ((t & 63) == 0) wred[t >> 6] = kb;
      __syncthreads();
      if (t == 0) {
        u64 bmin = wred[0];
#pragma unroll
        for (int wv = 1; wv < 4; ++wv) if (wred[wv] < bmin) bmin = wred[wv];
        int rstar = (int)(bmin & 255);
        if (rstar >= F) rstar = 0;
        int cstar = rcol[rstar];
        sc_star = cstar;
        int i = sFR5[rstar], j = sFC5[cstar];
        rm[i] = j; cm[j] = i;
        rkey[rstar] = ~0ull; cfree[cstar] = 0;
      }
      __syncthreads();
      int cs = sc_star;
      for (int r = t; r < F; r += 256) {
        if (rkey[r] != ~0ull && rcol[r] == cs) {
          const float* row = Csub + r * F;
          u64 bk = ~0ull; int bc = 0; int ig = sFR5[r];
          for (int c = 0; c < F; ++c) {
            if (!cfree[c]) continue;
            u64 k = (((u64)__float_as_uint(row[c])) << 24) | (u32)(ig * NN + sFC5[c]);
            if (k < bk) { bk = k; bc = c; }
          }
          rkey[r] = bk; rcol[r] = bc;
        }
      }
      __syncthreads();
    }
  } else if (F <= TGMAX && G != nullptr) {
    // ---- tier2: submatrix in global scratch, per-row cached minima ----
    for (int r = (t >> 6); r < F; r += 4) {
      const float* Ci = C + (size_t)sFR5[r] * NN;
      for (int c = (t & 63); c < F; c += 64) G[(size_t)r * F + c] = Ci[sFC5[c]];
    }
    for (int c = t; c < F; c += 256) cfree2[c] = 1;
    __syncthreads();
    for (int r = t; r < F; r += 256) {
      const float* row = G + (size_t)r * F;
      u64 bk = ~0ull; int bc = 0; int ig = sFR5[r];
      for (int c = 0; c < F; ++c) {
        u64 k = (((u64)__float_as_uint(row[c])) << 24) | (u32)(ig * NN + sFC5[c]);
        if (k < bk) { bk = k; bc = c; }
      }
      rkey2[r] = bk; rcol2[r] = bc;
    }
    __syncthreads();
    for (int it = 0; it < F; ++it) {
      u64 lv = ~0ull; int la = 0;
      for (int r = t; r < F; r += 256)
        if (rkey2[r] < lv) { lv = rkey2[r]; la = r; }
      red[t] = lv; redi[t] = la;
      __syncthreads();
      for (int s = 128; s > 0; s >>= 1) {
        if (t < s && red[t + s] < red[t]) { red[t] = red[t + s]; redi[t] = redi[t + s]; }
        __syncthreads();
      }
      if (t == 0) {
        int rstar = redi[0];
        int cstar = rcol2[rstar];
        sc_star = cstar;
        rm[sFR5[rstar]] = sFC5[cstar]; cm[sFC5[cstar]] = sFR5[rstar];
        rkey2[rstar] = ~0ull; cfree2[cstar] = 0;
        scnt = 0;
      }
      __syncthreads();
      int cs = sc_star;
      for (int r = t; r < F; r += 256)
        if (rkey2[r] != ~0ull && rcol2[r] == cs) { int p = atomicAdd(&scnt, 1); dl[p] = r; }
      __syncthreads();
      int nd = scnt;
      for (int d = 0; d < nd; ++d) {
        int r = dl[d];
        const float* Gr = G + (size_t)r * F;
        int ig = sFR5[r];
        u64 lb = ~0ull; int lc = 0;
        for (int c = t; c < F; c += 256) {
          if (!cfree2[c]) continue;
          u64 k = (((u64)__float_as_uint(Gr[c])) << 24) | (u32)(ig * NN + sFC5[c]);
          if (k < lb) { lb = k; lc = c; }
        }
        red[t] = lb; redi[t] = lc;
        __syncthreads();
        for (int s = 128; s > 0; s >>= 1) {
          if (t < s && red[t + s] < red[t]) { red[t] = red[t + s]; redi[t] = redi[t + s]; }
          __syncthreads();
        }
        if (t == 0) { rkey2[r] = red[0]; rcol2[r] = redi[0]; }
        __syncthreads();
      }
    }
  } else {
    for (int it = 0; it < NN; ++it) {
      if (t == 0) scnt = 0;
      __syncthreads();
      for (int i = t; i < NN; i += 256)
        if (rm[i] == -1) { int p = atomicAdd(&scnt, 1); FRg[p] = i; }
      __syncthreads();
      int Fa = scnt;
      if (Fa == 0) break;
      u64 best = ~0ull;
      int total = Fa * NN;
      for (int idx = t; idx < total; idx += 256) {
        int bb2 = idx >> 12, j = idx & 4095;
        if (cm[j] != -1) continue;
        int i = FRg[bb2];
        u64 key = pk(C[(size_t)i * NN + j], (u32)(i * NN + j));
        if (key < best) best = key;
      }
      red[t] = best;
      __syncthreads();
      for (int s = 128; s > 0; s >>= 1) {
        if (t < s) { if (red[t + s] < red[t]) red[t] = red[t + s]; }
        __syncthreads();
      }
      if (t == 0) {
        u32 lo = (u32)red[0];
        rm[lo >> 12] = lo & 4095; cm[lo & 4095] = lo >> 12;
      }
      __syncthreads();
    }
  }
}

// ---------- no-C fallback (proven round 1) ----------
template <bool USEC>
__global__ void k_rowpass(const float* __restrict__ C,
                          const float* __restrict__ x, const float* __restrict__ y,
                          const float* __restrict__ xx, const float* __restrict__ yy,
                          const int* __restrict__ cm, const int* __restrict__ FR,
                          const int* __restrict__ Fcnt, u64* __restrict__ rowbest) {
  int b = blockIdx.x;
  if (b >= *Fcnt) return;
  int i = FR[b];
  __shared__ float xsh[DD];
  __shared__ u64 red[256];
  int t = threadIdx.x;
  if (!USEC) { if (t < DD) xsh[t] = x[(size_t)i * DD + t]; }
  __syncthreads();
  float xxi = xx[i];
  u64 best = ~0ull;
  for (int j = t; j < NN; j += 256) {
    if (cm[j] != -1) continue;
    float d;
    if (USEC) {
      d = C[(size_t)i * NN + j];
    } else {
      const float* yj = y + (size_t)j * DD;
      float dot = 0.f;
#pragma unroll
      for (int k = 0; k < DD; ++k) dot = fmaf(xsh[k], yj[k], dot);
      float sq = (xxi + yy[j]) - 2.0f * dot;
      d = sqrtf(fmaxf(sq, 0.f));
    }
    u64 key = pk(d, (u32)j);
    if (key < best) best = key;
  }
  red[t] = best;
  __syncthreads();
  for (int s = 128; s > 0; s >>= 1) {
    if (t < s) { if (red[t + s] < red[t]) red[t] = red[t + s]; }
    __syncthreads();
  }
  if (t == 0) rowbest[i] = red[0];
}

template <bool USEC>
__global__ void k_colpass(const float* __restrict__ C,
                          const float* __restrict__ x, const float* __restrict__ y,
                          const float* __restrict__ xx, const float* __restrict__ yy,
                          const int* __restrict__ cm, const int* __restrict__ FR,
                          const int* __restrict__ Fcnt, u64* __restrict__ colpart) {
  int t = threadIdx.x;
  int j = blockIdx.x * 256 + t;
  int g = blockIdx.y;
  int F = *Fcnt;
  if (F == 0) return;
  int b0 = (g * F) / GCOL, b1 = ((g + 1) * F) / GCOL;
  u64 best = ~0ull;
  if (cm[j] == -1) {
    float yyj = yy[j];
    if (USEC) {
      for (int b = b0; b < b1; ++b) {
        int i = FR[b];
        u64 key = pk(C[(size_t)i * NN + j], (u32)i);
        if (key < best) best = key;
      }
    } else {
      float4 yr[16];
      const float4* yj4 = (const float4*)(y + (size_t)j * DD);
#pragma unroll
      for (int q = 0; q < 16; ++q) yr[q] = yj4[q];
      for (int b = b0; b < b1; ++b) {
        int i = FR[b];
        const float4* xi4 = (const float4*)(x + (size_t)i * DD);
        float dot = 0.f;
#pragma unroll
        for (int q = 0; q < 16; ++q) {
          float4 a = xi4[q], bb = yr[q];
          dot = fmaf(a.x, bb.x, dot); dot = fmaf(a.y, bb.y, dot);
          dot = fmaf(a.z, bb.z, dot); dot = fmaf(a.w, bb.w, dot);
        }
        float sq = (xx[i] + yyj) - 2.0f * dot;
        float d = sqrtf(fmaxf(sq, 0.f));
        u64 key = pk(d, (u32)i);
        if (key < best) best = key;
      }
    }
  }
  colpart[(size_t)g * NN + j] = best;
}

__global__ void k_accept(const u64* __restrict__ colpart, const u64* __restrict__ rowbest,
                         int* rm, int* cm, int* FR, int* Fcnt) {
  __shared__ int scnt;
  int t = threadIdx.x;
  if (*Fcnt == 0) return;
  for (int j = t; j < NN; j += 1024) {
    if (cm[j] != -1) continue;
    u64 best = ~0ull;
#pragma unroll
    for (int g = 0; g < GCOL; ++g) {
      u64 v = colpart[(size_t)g * NN + j];
      if (v < best) best = v;
    }
    u32 io = (u32)best;
    if (io >= NN) continue;
    int i = (int)io;
    if (rm[i] == -1 && (u32)(rowbest[i] & 0xffffffffu) == (u32)j) { rm[i] = j; cm[j] = i; }
  }
  __syncthreads();
  if (t == 0) scnt = 0;
  __syncthreads();
  for (int i = t; i < NN; i += 1024)
    if (rm[i] == -1) { int p = atomicAdd(&scnt, 1); FR[p] = i; }
  __syncthreads();
  if (t == 0) *Fcnt = scnt;
}

template <bool USEC>
__global__ void k_cleanup(const float* __restrict__ C,
                          const float* __restrict__ x, const float* __restrict__ y,
                          const float* __restrict__ xx, const float* __restrict__ yy,
                          int* rm, int* cm, int* FR) {
  __shared__ int scnt;
  __shared__ u64 red[1024];
  int t = threadIdx.x;
  for (int it = 0; it < NN; ++it) {
    if (t == 0) scnt = 0;
    __syncthreads();
    for (int i = t; i < NN; i += 1024)
      if (rm[i] == -1) { int p = atomicAdd(&scnt, 1); FR[p] = i; }
    __syncthreads();
    int F = scnt;
    if (F == 0) break;
    u64 best = ~0ull;
    int total = F * NN;
    for (int idx = t; idx < total; idx += 1024) {
      int b = idx >> 12;
      int j = idx & 4095;
      if (cm[j] != -1) continue;
      int i = FR[b];
      float d;
      if (USEC) d = C[(size_t)i * NN + j];
      else d = distfly(x, y, xx[i], yy[j], i, j);
      u64 key = pk(d, (u32)(i * NN + j));
      if (key < best) best = key;
    }
    red[t] = best;
    __syncthreads();
    for (int s = 512; s > 0; s >>= 1) {
      if (t < s) { if (red[t + s] < red[t]) red[t] = red[t + s]; }
      __syncthreads();
    }
    if (t == 0) {
      u32 lo = (u32)red[0];
      int i = lo >> 12, j = lo & 4095;
      rm[i] = j; cm[j] = i;
    }
    __syncthreads();
  }
}

extern "C" void kernel_launch(void* const* d_in, const int* in_sizes, int n_in,
                              void* d_out, int out_size, void* d_ws, size_t ws_size,
                              hipStream_t stream) {
  const float* x = (const float*)d_in[0];
  const float* y = (const float*)d_in[1];
  int* cm = (int*)d_out;

  char* w = (char*)d_ws;
  float* xx = (float*)(w + 0);
  float* yy = (float*)(w + 16384);
  int* rm = (int*)(w + 32768);
  int* FR = (int*)(w + 49152);
  int* Fcnt = (int*)(w + 65536);
  u64* rowbest = (u64*)(w + 65664);
  u64* rowpart = (u64*)(w + 98432);
  u64* colpart = (u64*)(w + 360704);
  float* C = (float*)(w + 1048576);
  u64* tilerow = (u64*)(w + 68157440);   // 2 MB; reused as endgame tier2 scratch
  u64* tilecol = (u64*)(w + 70254592);   // 2 MB

  size_t need_c = 1048576 + (size_t)NN * NN * 4;        // 68157440
  size_t need_seed = 68157440 + 2 * 2097152;            // 72351744
  bool usec = ws_size >= need_c;
  bool useseed = ws_size >= need_seed;

  k_init<<<dim3(16), 256, 0, stream>>>(x, y, xx, yy, rm, cm, FR, Fcnt,
                                       rowbest, rowpart, colpart);
  if (usec) {
    if (useseed) {
      k_build<true><<<dim3(64, 64), 256, 0, stream>>>(x, y, xx, yy, C, tilerow, tilecol);
      k_seed<<<dim3(32), 256, 0, stream>>>(tilerow, tilecol, rowbest, rowpart, colpart);
      k_accept3<<<dim3(16), 256, 0, stream>>>(colpart, rowbest, rm, cm, Fcnt);
    } else {
      k_build<false><<<dim3(64, 64), 256, 0, stream>>>(x, y, xx, yy, C, nullptr, nullptr);
    }
    for (int r = 0; r < NROUNDS; ++r) {
      k_round2<<<dim3(NN + 64 * CCH), 256, 0, stream>>>(C, rm, cm, rowbest, rowpart, colpart);
      k_accept3<<<dim3(16), 256, 0, stream>>>(colpart, rowbest, rm, cm, Fcnt);
    }
    k_endgame<<<dim3(1), 256, 0, stream>>>(C, rm, cm, FR,
                                           useseed ? (float*)tilerow : nullptr);
  } else {
    for (int r = 0; r < ROUNDS_FB; ++r) {
      k_rowpass<false><<<dim3(NN), 256, 0, stream>>>(nullptr, x, y, xx, yy, cm, FR, Fcnt, rowbest);
      k_colpass<false><<<dim3(16, GCOL), 256, 0, stream>>>(nullptr, x, y, xx, yy, cm, FR, Fcnt, colpart);
      k_accept<<<dim3(1), 1024, 0, stream>>>(colpart, rowbest, rm, cm, FR, Fcnt);
    }
    k_cleanup<false><<<dim3(1), 1024, 0, stream>>>(nullptr, x, y, xx, yy, rm, cm, FR);
  }
}

// Round 11
// 674.036 us; speedup vs baseline: 1560.5061x; 3.0596x over previous
//
#include <hip/hip_runtime.h>
#include <stdint.h>

#define NN 4096
#define DD 64
#define GCOL 16
#define CCH 16
#define RCHK 8
#define TMAX 112
#define TGMAX 512
#define NROUNDS 20
#define ROUNDS_FB 32

typedef unsigned long long u64;
typedef unsigned int u32;

#define RESC 0xFFFFFFFFFFFFFFFEull
#define EMPTY (~0ull)

__device__ __forceinline__ u64 pk(float d, u32 idx) {
  return (((u64)__float_as_uint(d)) << 32) | (u64)idx;
}

__device__ __forceinline__ float distfly(const float* __restrict__ x,
                                         const float* __restrict__ y,
                                         float xxi, float yyj, int i, int j) {
  const float* xi = x + (size_t)i * DD;
  const float* yj = y + (size_t)j * DD;
  float dot = 0.f;
#pragma unroll
  for (int k = 0; k < DD; ++k) dot = fmaf(xi[k], yj[k], dot);
  float sq = (xxi + yyj) - 2.0f * dot;
  return sqrtf(fmaxf(sq, 0.f));
}

__global__ void k_init(const float* __restrict__ x, const float* __restrict__ y,
                       float* xx, float* yy, int* rm, int* cm, int* FR, int* Fcnt,
                       u64* rowbest, u64* rowpart, u64* colpart) {
  int i = blockIdx.x * blockDim.x + threadIdx.x;
  if (i < NN) {
    const float* xi = x + (size_t)i * DD;
    const float* yi = y + (size_t)i * DD;
    float sx = 0.f, sy = 0.f;
#pragma unroll
    for (int k = 0; k < DD; ++k) { sx = fmaf(xi[k], xi[k], sx); sy = fmaf(yi[k], yi[k], sy); }
    xx[i] = sx; yy[i] = sy;
    rm[i] = -1; cm[i] = -1; FR[i] = i;
    rowbest[i] = EMPTY;                      // stale -> full rescan in round 1
#pragma unroll
    for (int h = 0; h < RCHK; ++h) rowpart[(size_t)h * NN + i] = RESC;
#pragma unroll
    for (int g = 0; g < CCH; ++g) colpart[(size_t)g * NN + i] = RESC;
    if (i == 0) *Fcnt = NN;
  }
}

// C[i][j] = sqrt(max(xx[i]+yy[j]-2*dot, 0)), 64x64 tiles.
// EXACT round-5 kernel: measured 69us / 72MB. No SEED fusion (scratch-traffic trap).
__global__ void k_build(const float* __restrict__ x, const float* __restrict__ y,
                        const float* __restrict__ xx, const float* __restrict__ yy,
                        float* __restrict__ C) {
  __shared__ float xs[64][65];
  __shared__ float ys[64][65];
  int t = threadIdx.x;
  int bi = blockIdx.y * 64, bj = blockIdx.x * 64;
  for (int e = t; e < 64 * 64; e += 256) {
    int r = e >> 6, c = e & 63;
    xs[r][c] = x[(size_t)(bi + r) * DD + c];
    ys[r][c] = y[(size_t)(bj + r) * DD + c];
  }
  __syncthreads();
  int tx = t & 15, ty = t >> 4;
  float acc[4][4];
#pragma unroll
  for (int r = 0; r < 4; ++r)
#pragma unroll
    for (int c = 0; c < 4; ++c) acc[r][c] = 0.f;
#pragma unroll
  for (int k = 0; k < 64; ++k) {
    float a[4], b[4];
#pragma unroll
    for (int r = 0; r < 4; ++r) a[r] = xs[ty * 4 + r][k];
#pragma unroll
    for (int c = 0; c < 4; ++c) b[c] = ys[tx * 4 + c][k];
#pragma unroll
    for (int r = 0; r < 4; ++r)
#pragma unroll
      for (int c = 0; c < 4; ++c) acc[r][c] = fmaf(a[r], b[c], acc[r][c]);
  }
#pragma unroll
  for (int r = 0; r < 4; ++r) {
    int i = bi + ty * 4 + r;
    float xxi = xx[i];
    float4 v;
    float* vp = (float*)&v;
#pragma unroll
    for (int c = 0; c < 4; ++c) {
      int j = bj + tx * 4 + c;
      float sq = (xxi + yy[j]) - 2.0f * acc[r][c];
      vp[c] = sqrtf(fmaxf(sq, 0.f));
    }
    *(float4*)(C + (size_t)i * NN + bj + tx * 4) = v;
  }
}

// Refresh (proven rounds 6/9/10): blocks [0,NN) rows (chunked), [NN,NN+1024) col-chunks.
__global__ void k_round2(const float* __restrict__ C, const int* __restrict__ rm,
                         const int* __restrict__ cm, u64* __restrict__ rowbest,
                         u64* __restrict__ rowpart, u64* __restrict__ colpart) {
  __shared__ u64 red[256];
  __shared__ u64 rp[RCHK];
  __shared__ int stale[RCHK];
  __shared__ u64 part[4][64];
  int b = blockIdx.x;
  int t = threadIdx.x;
  if (b < NN) {
    int i = b;
    if (rm[i] != -1) return;
    u64 rb = rowbest[i];
    u32 jb = (u32)rb;
    if (jb < NN && cm[jb] == -1) return;
    if (t < RCHK) {
      u64 e = rowpart[(size_t)t * NN + i];
      rp[t] = e;
      u32 je = (u32)e;
      stale[t] = (e != EMPTY) && !(je < NN && cm[je] == -1);
    }
    __syncthreads();
    const float* Ci = C + (size_t)i * NN;
    for (int h = 0; h < RCHK; ++h) {
      if (!stale[h]) continue;
      int j0 = h * 512 + t * 2;
      float2 v = *(const float2*)(Ci + j0);
      int2 m = *(const int2*)(cm + j0);
      u64 best = EMPTY;
      if (m.x == -1) best = pk(v.x, (u32)j0);
      if (m.y == -1) { u64 k2 = pk(v.y, (u32)(j0 + 1)); if (k2 < best) best = k2; }
      red[t] = best;
      __syncthreads();
      for (int s = 128; s > 0; s >>= 1) {
        if (t < s) { if (red[t + s] < red[t]) red[t] = red[t + s]; }
        __syncthreads();
      }
      if (t == 0) { rp[h] = red[0]; rowpart[(size_t)h * NN + i] = red[0]; }
      __syncthreads();
    }
    if (t == 0) {
      u64 best = rp[0];
#pragma unroll
      for (int h = 1; h < RCHK; ++h) if (rp[h] < best) best = rp[h];
      rowbest[i] = best;
    }
  } else {
    int idx = b - NN;
    int cb = idx & 63, g = idx >> 6;
    int lane = t & 63, s = t >> 6;
    int j = cb * 64 + lane;
    u64* slot = colpart + (size_t)g * NN + j;
    bool stale_c = false;
    if (cm[j] == -1) {
      u64 e = *slot;
      if (e != EMPTY) { u32 io = (u32)e; stale_c = !(io < NN && rm[io] == -1); }
    }
    u64 best = EMPTY;
    if (stale_c) {
      int i0 = g * 256 + s * 64;
      for (int i = i0; i < i0 + 64; ++i) {
        if (rm[i] != -1) continue;
        u64 key = pk(C[(size_t)i * NN + j], (u32)i);
        if (key < best) best = key;
      }
    }
    part[s][lane] = best;
    __syncthreads();
    if (s == 0 && stale_c) {
      u64 b0 = part[0][lane];
#pragma unroll
      for (int q = 1; q < 4; ++q) if (part[q][lane] < b0) b0 = part[q][lane];
      *slot = b0;
    }
  }
}

__global__ void k_accept3(const u64* __restrict__ colpart, const u64* __restrict__ rowbest,
                          int* rm, int* cm, int* Fcnt) {
  if (*Fcnt == 0) return;
  int j = blockIdx.x * 256 + threadIdx.x;
  if (cm[j] != -1) return;
  u64 best = EMPTY;
#pragma unroll
  for (int g = 0; g < CCH; ++g) {
    u64 v = colpart[(size_t)g * NN + j];
    if (v < best) best = v;
  }
  u32 io = (u32)best;
  if (io >= NN) return;
  int i = (int)io;
  if (rm[i] == -1 && (u32)(rowbest[i] & 0xffffffffu) == (u32)j) {
    rm[i] = j; cm[j] = i;
    atomicSub(Fcnt, 1);
  }
}

// Endgame, 3 tiers (proven round 10): F<=TMAX LDS greedy; F<=TGMAX global-submatrix
// greedy with cached row minima (G scratch, may be null); else bounded fallback.
__global__ __launch_bounds__(256) void k_endgame(const float* __restrict__ C,
                                                 int* rm, int* cm, int* FRg,
                                                 float* __restrict__ G) {
  __shared__ __align__(16) char shb[54272];
  int* sFR5 = (int*)shb;
  int* sFC5 = (int*)(shb + 2048);
  float* Csub = (float*)(shb + 4096);
  u64* rkey2 = (u64*)(shb + 4096);
  int* rcol2 = (int*)(shb + 8192);
  int* cfree2 = (int*)(shb + 10240);
  int* dl = (int*)(shb + 12288);
  __shared__ int sF, sG, sc_star, scnt;
  __shared__ u64 rkey[TMAX];
  __shared__ int rcol[TMAX];
  __shared__ int cfree[TMAX];
  __shared__ u64 wred[4];
  __shared__ u64 red[256];
  __shared__ int redi[256];
  int t = threadIdx.x;
  if (t == 0) { sF = 0; sG = 0; }
  __syncthreads();
  for (int i = t; i < NN; i += 256)
    if (rm[i] == -1) { int p = atomicAdd(&sF, 1); if (p < TGMAX) sFR5[p] = i; }
  for (int j = t; j < NN; j += 256)
    if (cm[j] == -1) { int p = atomicAdd(&sG, 1); if (p < TGMAX) sFC5[p] = j; }
  __syncthreads();
  int F = sF;
  if (F == 0) return;
  if (F <= TMAX) {
    for (int r = (t >> 6); r < F; r += 4) {
      const float* Ci = C + (size_t)sFR5[r] * NN;
      for (int c = (t & 63); c < F; c += 64) Csub[r * F + c] = Ci[sFC5[c]];
    }
    for (int c = t; c < F; c += 256) cfree[c] = 1;
    __syncthreads();
    for (int r = t; r < F; r += 256) {
      const float* row = Csub + r * F;
      u64 bk = ~0ull; int bc = 0; int ig = sFR5[r];
      for (int c = 0; c < F; ++c) {
        u64 k = (((u64)__float_as_uint(row[c])) << 24) | (u32)(ig * NN + sFC5[c]);
        if (k < bk) { bk = k; bc = c; }
      }
      rkey[r] = bk; rcol[r] = bc;
    }
    __syncthreads();
    for (int it = 0; it < F; ++it) {
      u64 kb = ~0ull;
      if (t < F && rkey[t] != ~0ull) kb = (rkey[t] << 8) | (u64)(u32)t;
      for (int s = 32; s > 0; s >>= 1) {
        u64 o = __shfl_down(kb, s, 64);
        if (o < kb) kb = o;
      }
      if ((t & 63) == 0) wred[t >> 6] = kb;
      __syncthreads();
      if (t == 0) {
        u64 bmin = wred[0];
#pragma unroll
        for (int wv = 1; wv < 4; ++wv) if (wred[wv] < bmin) bmin = wred[wv];
        int rstar = (int)(bmin & 255);
        if (rstar >= F) rstar = 0;
        int cstar = rcol[rstar];
        sc_star = cstar;
        int i = sFR5[rstar], j = sFC5[cstar];
        rm[i] = j; cm[j] = i;
        rkey[rstar] = ~0ull; cfree[cstar] = 0;
      }
      __syncthreads();
      int cs = sc_star;
      for (int r = t; r < F; r += 256) {
        if (rkey[r] != ~0ull && rcol[r] == cs) {
          const float* row = Csub + r * F;
          u64 bk = ~0ull; int bc = 0; int ig = sFR5[r];
          for (int c = 0; c < F; ++c) {
            if (!cfree[c]) continue;
            u64 k = (((u64)__float_as_uint(row[c])) << 24) | (u32)(ig * NN + sFC5[c]);
            if (k < bk) { bk = k; bc = c; }
          }
          rkey[r] = bk; rcol[r] = bc;
        }
      }
      __syncthreads();
    }
  } else if (F <= TGMAX && G != nullptr) {
    for (int r = (t >> 6); r < F; r += 4) {
      const float* Ci = C + (size_t)sFR5[r] * NN;
      for (int c = (t & 63); c < F; c += 64) G[(size_t)r * F + c] = Ci[sFC5[c]];
    }
    for (int c = t; c < F; c += 256) cfree2[c] = 1;
    __syncthreads();
    for (int r = t; r < F; r += 256) {
      const float* row = G + (size_t)r * F;
      u64 bk = ~0ull; int bc = 0; int ig = sFR5[r];
      for (int c = 0; c < F; ++c) {
        u64 k = (((u64)__float_as_uint(row[c])) << 24) | (u32)(ig * NN + sFC5[c]);
        if (k < bk) { bk = k; bc = c; }
      }
      rkey2[r] = bk; rcol2[r] = bc;
    }
    __syncthreads();
    for (int it = 0; it < F; ++it) {
      u64 lv = ~0ull; int la = 0;
      for (int r = t; r < F; r += 256)
        if (rkey2[r] < lv) { lv = rkey2[r]; la = r; }
      red[t] = lv; redi[t] = la;
      __syncthreads();
      for (int s = 128; s > 0; s >>= 1) {
        if (t < s && red[t + s] < red[t]) { red[t] = red[t + s]; redi[t] = redi[t + s]; }
        __syncthreads();
      }
      if (t == 0) {
        int rstar = redi[0];
        int cstar = rcol2[rstar];
        sc_star = cstar;
        rm[sFR5[rstar]] = sFC5[cstar]; cm[sFC5[cstar]] = sFR5[rstar];
        rkey2[rstar] = ~0ull; cfree2[cstar] = 0;
        scnt = 0;
      }
      __syncthreads();
      int cs = sc_star;
      for (int r = t; r < F; r += 256)
        if (rkey2[r] != ~0ull && rcol2[r] == cs) { int p = atomicAdd(&scnt, 1); dl[p] = r; }
      __syncthreads();
      int nd = scnt;
      for (int d = 0; d < nd; ++d) {
        int r = dl[d];
        const float* Gr = G + (size_t)r * F;
        int ig = sFR5[r];
        u64 lb = ~0ull; int lc = 0;
        for (int c = t; c < F; c += 256) {
          if (!cfree2[c]) continue;
          u64 k = (((u64)__float_as_uint(Gr[c])) << 24) | (u32)(ig * NN + sFC5[c]);
          if (k < lb) { lb = k; lc = c; }
        }
        red[t] = lb; redi[t] = lc;
        __syncthreads();
        for (int s = 128; s > 0; s >>= 1) {
          if (t < s && red[t + s] < red[t]) { red[t] = red[t + s]; redi[t] = redi[t + s]; }
          __syncthreads();
        }
        if (t == 0) { rkey2[r] = red[0]; rcol2[r] = redi[0]; }
        __syncthreads();
      }
    }
  } else {
    for (int it = 0; it < NN; ++it) {
      if (t == 0) scnt = 0;
      __syncthreads();
      for (int i = t; i < NN; i += 256)
        if (rm[i] == -1) { int p = atomicAdd(&scnt, 1); FRg[p] = i; }
      __syncthreads();
      int Fa = scnt;
      if (Fa == 0) break;
      u64 best = ~0ull;
      int total = Fa * NN;
      for (int idx = t; idx < total; idx += 256) {
        int bb2 = idx >> 12, j = idx & 4095;
        if (cm[j] != -1) continue;
        int i = FRg[bb2];
        u64 key = pk(C[(size_t)i * NN + j], (u32)(i * NN + j));
        if (key < best) best = key;
      }
      red[t] = best;
      __syncthreads();
      for (int s = 128; s > 0; s >>= 1) {
        if (t < s) { if (red[t + s] < red[t]) red[t] = red[t + s]; }
        __syncthreads();
      }
      if (t == 0) {
        u32 lo = (u32)red[0];
        rm[lo >> 12] = lo & 4095; cm[lo & 4095] = lo >> 12;
      }
      __syncthreads();
    }
  }
}

// ---------- no-C fallback (proven round 1) ----------
template <bool USEC>
__global__ void k_rowpass(const float* __restrict__ C,
                          const float* __restrict__ x, const float* __restrict__ y,
                          const float* __restrict__ xx, const float* __restrict__ yy,
                          const int* __restrict__ cm, const int* __restrict__ FR,
                          const int* __restrict__ Fcnt, u64* __restrict__ rowbest) {
  int b = blockIdx.x;
  if (b >= *Fcnt) return;
  int i = FR[b];
  __shared__ float xsh[DD];
  __shared__ u64 red[256];
  int t = threadIdx.x;
  if (!USEC) { if (t < DD) xsh[t] = x[(size_t)i * DD + t]; }
  __syncthreads();
  float xxi = xx[i];
  u64 best = ~0ull;
  for (int j = t; j < NN; j += 256) {
    if (cm[j] != -1) continue;
    float d;
    if (USEC) {
      d = C[(size_t)i * NN + j];
    } else {
      const float* yj = y + (size_t)j * DD;
      float dot = 0.f;
#pragma unroll
      for (int k = 0; k < DD; ++k) dot = fmaf(xsh[k], yj[k], dot);
      float sq = (xxi + yy[j]) - 2.0f * dot;
      d = sqrtf(fmaxf(sq, 0.f));
    }
    u64 key = pk(d, (u32)j);
    if (key < best) best = key;
  }
  red[t] = best;
  __syncthreads();
  for (int s = 128; s > 0; s >>= 1) {
    if (t < s) { if (red[t + s] < red[t]) red[t] = red[t + s]; }
    __syncthreads();
  }
  if (t == 0) rowbest[i] = red[0];
}

template <bool USEC>
__global__ void k_colpass(const float* __restrict__ C,
                          const float* __restrict__ x, const float* __restrict__ y,
                          const float* __restrict__ xx, const float* __restrict__ yy,
                          const int* __restrict__ cm, const int* __restrict__ FR,
                          const int* __restrict__ Fcnt, u64* __restrict__ colpart) {
  int t = threadIdx.x;
  int j = blockIdx.x * 256 + t;
  int g = blockIdx.y;
  int F = *Fcnt;
  if (F == 0) return;
  int b0 = (g * F) / GCOL, b1 = ((g + 1) * F) / GCOL;
  u64 best = ~0ull;
  if (cm[j] == -1) {
    float yyj = yy[j];
    if (USEC) {
      for (int b = b0; b < b1; ++b) {
        int i = FR[b];
        u64 key = pk(C[(size_t)i * NN + j], (u32)i);
        if (key < best) best = key;
      }
    } else {
      float4 yr[16];
      const float4* yj4 = (const float4*)(y + (size_t)j * DD);
#pragma unroll
      for (int q = 0; q < 16; ++q) yr[q] = yj4[q];
      for (int b = b0; b < b1; ++b) {
        int i = FR[b];
        const float4* xi4 = (const float4*)(x + (size_t)i * DD);
        float dot = 0.f;
#pragma unroll
        for (int q = 0; q < 16; ++q) {
          float4 a = xi4[q], bb = yr[q];
          dot = fmaf(a.x, bb.x, dot); dot = fmaf(a.y, bb.y, dot);
          dot = fmaf(a.z, bb.z, dot); dot = fmaf(a.w, bb.w, dot);
        }
        float sq = (xx[i] + yyj) - 2.0f * dot;
        float d = sqrtf(fmaxf(sq, 0.f));
        u64 key = pk(d, (u32)i);
        if (key < best) best = key;
      }
    }
  }
  colpart[(size_t)g * NN + j] = best;
}

__global__ void k_accept(const u64* __restrict__ colpart, const u64* __restrict__ rowbest,
                         int* rm, int* cm, int* FR, int* Fcnt) {
  __shared__ int scnt;
  int t = threadIdx.x;
  if (*Fcnt == 0) return;
  for (int j = t; j < NN; j += 1024) {
    if (cm[j] != -1) continue;
    u64 best = ~0ull;
#pragma unroll
    for (int g = 0; g < GCOL; ++g) {
      u64 v = colpart[(size_t)g * NN + j];
      if (v < best) best = v;
    }
    u32 io = (u32)best;
    if (io >= NN) continue;
    int i = (int)io;
    if (rm[i] == -1 && (u32)(rowbest[i] & 0xffffffffu) == (u32)j) { rm[i] = j; cm[j] = i; }
  }
  __syncthreads();
  if (t == 0) scnt = 0;
  __syncthreads();
  for (int i = t; i < NN; i += 1024)
    if (rm[i] == -1) { int p = atomicAdd(&scnt, 1); FR[p] = i; }
  __syncthreads();
  if (t == 0) *Fcnt = scnt;
}

template <bool USEC>
__global__ void k_cleanup(const float* __restrict__ C,
                          const float* __restrict__ x, const float* __restrict__ y,
                          const float* __restrict__ xx, const float* __restrict__ yy,
                          int* rm, int* cm, int* FR) {
  __shared__ int scnt;
  __shared__ u64 red[1024];
  int t = threadIdx.x;
  for (int it = 0; it < NN; ++it) {
    if (t == 0) scnt = 0;
    __syncthreads();
    for (int i = t; i < NN; i += 1024)
      if (rm[i] == -1) { int p = atomicAdd(&scnt, 1); FR[p] = i; }
    __syncthreads();
    int F = scnt;
    if (F == 0) break;
    u64 best = ~0ull;
    int total = F * NN;
    for (int idx = t; idx < total; idx += 1024) {
      int b = idx >> 12;
      int j = idx & 4095;
      if (cm[j] != -1) continue;
      int i = FR[b];
      float d;
      if (USEC) d = C[(size_t)i * NN + j];
      else d = distfly(x, y, xx[i], yy[j], i, j);
      u64 key = pk(d, (u32)(i * NN + j));
      if (key < best) best = key;
    }
    red[t] = best;
    __syncthreads();
    for (int s = 512; s > 0; s >>= 1) {
      if (t < s) { if (red[t + s] < red[t]) red[t] = red[t + s]; }
      __syncthreads();
    }
    if (t == 0) {
      u32 lo = (u32)red[0];
      int i = lo >> 12, j = lo & 4095;
      rm[i] = j; cm[j] = i;
    }
    __syncthreads();
  }
}

extern "C" void kernel_launch(void* const* d_in, const int* in_sizes, int n_in,
                              void* d_out, int out_size, void* d_ws, size_t ws_size,
                              hipStream_t stream) {
  const float* x = (const float*)d_in[0];
  const float* y = (const float*)d_in[1];
  int* cm = (int*)d_out;

  char* w = (char*)d_ws;
  float* xx = (float*)(w + 0);
  float* yy = (float*)(w + 16384);
  int* rm = (int*)(w + 32768);
  int* FR = (int*)(w + 49152);
  int* Fcnt = (int*)(w + 65536);
  u64* rowbest = (u64*)(w + 65664);
  u64* rowpart = (u64*)(w + 98432);
  u64* colpart = (u64*)(w + 360704);
  float* C = (float*)(w + 1048576);
  float* G = (float*)(w + 68157440);             // 1 MB endgame tier2 scratch

  size_t need_c = 1048576 + (size_t)NN * NN * 4; // 68157440
  size_t need_g = 68157440 + (size_t)TGMAX * TGMAX * 4;  // +1 MB
  bool usec = ws_size >= need_c;
  bool useg = ws_size >= need_g;

  k_init<<<dim3(16), 256, 0, stream>>>(x, y, xx, yy, rm, cm, FR, Fcnt,
                                       rowbest, rowpart, colpart);
  if (usec) {
    k_build<<<dim3(64, 64), 256, 0, stream>>>(x, y, xx, yy, C);
    for (int r = 0; r < NROUNDS; ++r) {
      k_round2<<<dim3(NN + 64 * CCH), 256, 0, stream>>>(C, rm, cm, rowbest, rowpart, colpart);
      k_accept3<<<dim3(16), 256, 0, stream>>>(colpart, rowbest, rm, cm, Fcnt);
    }
    k_endgame<<<dim3(1), 256, 0, stream>>>(C, rm, cm, FR, useg ? G : nullptr);
  } else {
    for (int r = 0; r < ROUNDS_FB; ++r) {
      k_rowpass<false><<<dim3(NN), 256, 0, stream>>>(nullptr, x, y, xx, yy, cm, FR, Fcnt, rowbest);
      k_colpass<false><<<dim3(16, GCOL), 256, 0, stream>>>(nullptr, x, y, xx, yy, cm, FR, Fcnt, colpart);
      k_accept<<<dim3(1), 1024, 0, stream>>>(colpart, rowbest, rm, cm, FR, Fcnt);
    }
    k_cleanup<false><<<dim3(1), 1024, 0, stream>>>(nullptr, x, y, xx, yy, rm, cm, FR);
  }
}